// Round 10
// baseline (90.650 us; speedup 1.0000x reference)
//
#include <hip/hip_runtime.h>

// ContrastiveLoss: B=16, C=256, H=32, Wd=32, K=5, SKIP=1, NEG=16
//   1) transpose: z -> ztr (bf16 frag-major, 16B stores); c -> ct8 (fp8); W -> Wbf
//   2) MFMA GEMM (flat 1120-block grid, reg dbuf K loop, preloaded ct8), fp8 out
//      + fused positive hinge partial
//   3) score: 8 waves/block, wave per position, per-wave partial (no barrier)
//   4) single reduction over [score 71680 | gemm 1120] partials -> d_out[0]

typedef unsigned short u16;
typedef unsigned char u8;
typedef unsigned int u32;
typedef __attribute__((ext_vector_type(8))) short bf16x8;
typedef __attribute__((ext_vector_type(4))) float f32x4;
typedef __attribute__((ext_vector_type(2))) float f32x2;

#define NEG_  16
#define MAXN_ 15360   // (32-1-1)*32*16
#define TOTROWS 71680 // sum_k (30-kidx)*512
#define NPOSP  1120   // flattened gemm blocks
#define NPARTS (TOTROWS + NPOSP)

__device__ __forceinline__ u16 f2bf(float f) {
    union { u32 i; float f; } v; v.f = f;
    u32 b = v.i;
    return (u16)((b + 0x7FFFu + ((b >> 16) & 1u)) >> 16);
}
__device__ __forceinline__ u32 f2bf2(float lo, float hi) {
    return (u32)f2bf(lo) | ((u32)f2bf(hi) << 16);
}

__device__ __forceinline__ size_t frag_addr(int row, int k) {
    return ((size_t)(row >> 4) * 8 + (k >> 5)) * 512
         + (size_t)((row & 15) + 16 * ((k >> 3) & 3)) * 8 + (k & 7);
}

// ---------------- transpose + wconv ----------------
// z==0: z -> ztr (bf16 frag-major, one 16B store/thread)
// z==1: c -> ct8 (fp8, y<30); z==2: W -> Wbf (frag-major)
__global__ __launch_bounds__(256) void transpose_kernel(
    const float* __restrict__ z, const float* __restrict__ cc,
    const float* __restrict__ W,
    u16* __restrict__ ztr, u8* __restrict__ ct8, u16* __restrict__ Wbf)
{
    int tid = threadIdx.x;
    if (blockIdx.z == 2) {
        if (blockIdx.y != 0 || blockIdx.x >= 320) return;
        int i4 = blockIdx.x * 256 + tid;
        float4 v = reinterpret_cast<const float4*>(W)[i4];
        int e = i4 * 4;
        int kw = e >> 16;
        int rem = e & 65535;
        int o = rem >> 8, c = rem & 255;
        size_t base = (size_t)kw * 65536 + frag_addr(o, c);
        ushort4 u;
        u.x = f2bf(v.x); u.y = f2bf(v.y); u.z = f2bf(v.z); u.w = f2bf(v.w);
        *reinterpret_cast<ushort4*>(Wbf + base) = u;
        return;
    }
    int by = blockIdx.x;
    int b = by >> 5, y = by & 31;
    int c0 = blockIdx.y * 64;
    bool is_c = (blockIdx.z == 1);
    if (is_c && y >= 30) return;
    const float* src = is_c ? cc : z;

    __shared__ float ts[64][33];
    int x = tid & 31, ci0 = tid >> 5;
#pragma unroll
    for (int i = 0; i < 8; ++i) {
        int ci = ci0 + i * 8;
        ts[ci][x] = src[(((size_t)b * 256 + c0 + ci) * 32 + y) * 32 + x];
    }
    __syncthreads();
    if (is_c) {
        int cw = tid & 63, xw0 = tid >> 6;
#pragma unroll
        for (int i = 0; i < 8; ++i) {
            int xw = xw0 + i * 4;
            float v = ts[cw][xw];
            u32 pk = __builtin_amdgcn_cvt_pk_fp8_f32(v, v, 0, false);
            ct8[(((size_t)y * 32 + xw) * 16 + b) * 256 + c0 + cw] = (u8)pk;
        }
    } else {
        // one 16B frag-major store per thread: 8 consecutive chans of one (y,x,b)
        int g = tid >> 5;                 // chan-octet 0..7
        int row = (y * 32 + x) * 16 + b;
        int k0 = c0 + g * 8;
        uint4 w;
        w.x = f2bf2(ts[g * 8 + 0][x], ts[g * 8 + 1][x]);
        w.y = f2bf2(ts[g * 8 + 2][x], ts[g * 8 + 3][x]);
        w.z = f2bf2(ts[g * 8 + 4][x], ts[g * 8 + 5][x]);
        w.w = f2bf2(ts[g * 8 + 6][x], ts[g * 8 + 7][x]);
        *reinterpret_cast<uint4*>(ztr + frag_addr(row, k0)) = w;
    }
}

// ---------------- MFMA GEMM, fp8 out + fused positive ----------------
__global__ __launch_bounds__(256) void gemm_mfma_kernel(
    const u16* __restrict__ ztr, const u16* __restrict__ Wbf,
    const u8* __restrict__ ct8,
    u8* __restrict__ ztwk8, float* __restrict__ posPart)
{
    int flat = blockIdx.x;
    int kidx, base;
    if (flat < 240)      { kidx = 0; base = 0; }
    else if (flat < 472) { kidx = 1; base = 240; }
    else if (flat < 696) { kidx = 2; base = 472; }
    else if (flat < 912) { kidx = 3; base = 696; }
    else                 { kidx = 4; base = 912; }
    int row0 = (flat - base) * 64;
    int offk = 512 * (30 * kidx - (kidx * (kidx - 1)) / 2);

    int tile0 = (((kidx + 2) * 512 + row0) >> 4);
    const u16* Bsw = Wbf + (size_t)kidx * 65536;
    u8* out = ztwk8 + ((size_t)offk + row0) * 256;

    int wid = threadIdx.x >> 6, lane = threadIdx.x & 63;
    int col0 = wid * 64;
    int lr = lane & 15;
    int rq = (lane >> 4) * 4;

    const u16* Abase = ztr + (size_t)tile0 * 8 * 512 + lane * 8;
    const u16* Bbase = Bsw + (size_t)wid * 4 * 8 * 512 + lane * 8;

    // preload positive-ctx words (hoisted; arrive during MFMA loop)
    u32 cw[4][4];
#pragma unroll
    for (int i = 0; i < 4; ++i)
#pragma unroll
        for (int j = 0; j < 4; ++j)
            cw[i][j] = *reinterpret_cast<const u32*>(
                ct8 + (size_t)(row0 + i * 16 + lr) * 256 + col0 + j * 16 + rq);

    f32x4 acc[4][4] = {};
    bf16x8 a[4], b[4];

#pragma unroll
    for (int i = 0; i < 4; ++i)
        a[i] = *reinterpret_cast<const bf16x8*>(Abase + (size_t)i * 8 * 512);
#pragma unroll
    for (int j = 0; j < 4; ++j)
        b[j] = *reinterpret_cast<const bf16x8*>(Bbase + (size_t)j * 8 * 512);

#pragma unroll
    for (int kb = 0; kb < 8; ++kb) {
        bf16x8 a2[4], b2[4];
        if (kb < 7) {
#pragma unroll
            for (int i = 0; i < 4; ++i)
                a2[i] = *reinterpret_cast<const bf16x8*>(Abase + ((size_t)i * 8 + kb + 1) * 512);
#pragma unroll
            for (int j = 0; j < 4; ++j)
                b2[j] = *reinterpret_cast<const bf16x8*>(Bbase + ((size_t)j * 8 + kb + 1) * 512);
        }
#pragma unroll
        for (int i = 0; i < 4; ++i)
#pragma unroll
            for (int j = 0; j < 4; ++j)
                acc[i][j] = __builtin_amdgcn_mfma_f32_16x16x32_bf16(b[j], a[i], acc[i][j], 0, 0, 0);
        if (kb < 7) {
#pragma unroll
            for (int i = 0; i < 4; ++i) a[i] = a2[i];
#pragma unroll
            for (int j = 0; j < 4; ++j) b[j] = b2[j];
        }
    }

    __shared__ float pos[4][64];

#pragma unroll
    for (int i = 0; i < 4; ++i) {
        float pp = 0.f;
#pragma unroll
        for (int j = 0; j < 4; ++j) {
            u32 u = 0;
            u = __builtin_amdgcn_cvt_pk_fp8_f32(acc[i][j][0], acc[i][j][1], u, false);
            u = __builtin_amdgcn_cvt_pk_fp8_f32(acc[i][j][2], acc[i][j][3], u, true);
            *reinterpret_cast<u32*>(out + (size_t)(i * 16 + lr) * 256 + col0 + j * 16 + rq) = u;
            f32x2 clo = __builtin_amdgcn_cvt_pk_f32_fp8(cw[i][j], false);
            f32x2 chi = __builtin_amdgcn_cvt_pk_f32_fp8(cw[i][j], true);
            pp = fmaf(acc[i][j][0], clo.x, pp);
            pp = fmaf(acc[i][j][1], clo.y, pp);
            pp = fmaf(acc[i][j][2], chi.x, pp);
            pp = fmaf(acc[i][j][3], chi.y, pp);
        }
        pp += __shfl_xor(pp, 16);
        pp += __shfl_xor(pp, 32);
        if (lane < 16) pos[wid][i * 16 + lane] = pp;
    }
    __syncthreads();

    if (threadIdx.x < 64) {
        float p = pos[0][threadIdx.x] + pos[1][threadIdx.x]
                + pos[2][threadIdx.x] + pos[3][threadIdx.x];
        float Nk = (float)((30 - kidx) * 512);
        float h = fmaxf(0.f, 1.f - p) / Nk;
#pragma unroll
        for (int s = 1; s < 64; s <<= 1) h += __shfl_xor(h, s);
        if (threadIdx.x == 0) posPart[flat] = h;
    }
}

// ---------------- negative scores + hinge ----------------
__device__ __forceinline__ float dot16(uint4 nb, const f32x2* cp) {
    f32x2 d0 = {0.f, 0.f}, d1 = {0.f, 0.f};
    d0 += __builtin_amdgcn_cvt_pk_f32_fp8(nb.x, false) * cp[0];
    d1 += __builtin_amdgcn_cvt_pk_f32_fp8(nb.x, true)  * cp[1];
    d0 += __builtin_amdgcn_cvt_pk_f32_fp8(nb.y, false) * cp[2];
    d1 += __builtin_amdgcn_cvt_pk_f32_fp8(nb.y, true)  * cp[3];
    d0 += __builtin_amdgcn_cvt_pk_f32_fp8(nb.z, false) * cp[4];
    d1 += __builtin_amdgcn_cvt_pk_f32_fp8(nb.z, true)  * cp[5];
    d0 += __builtin_amdgcn_cvt_pk_f32_fp8(nb.w, false) * cp[6];
    d1 += __builtin_amdgcn_cvt_pk_f32_fp8(nb.w, true)  * cp[7];
    f32x2 d = d0 + d1;
    return d.x + d.y;
}

// 8 waves/block, wave per position; lane = (r = neg-slot, c16 = chunk).
// XCD-chunked swizzle: 8960 blocks = 8 * 1120. Per-wave partial, no barrier.
__global__ __launch_bounds__(512) void score_kernel(
    const u8* __restrict__ ztwk8, const u8* __restrict__ ct8,
    const int* __restrict__ rind, float* __restrict__ partials)
{
    int bid = blockIdx.x;
    int swb = (bid & 7) * 1120 + (bid >> 3);
    int wid = threadIdx.x >> 6, lane = threadIdx.x & 63;
    int gp = swb * 8 + wid;

    const int ends0 = 15360, ends1 = 30208, ends2 = 44544, ends3 = 58368;
    int kidx, off;
    if (gp < ends0)      { kidx = 0; off = 0; }
    else if (gp < ends1) { kidx = 1; off = ends0; }
    else if (gp < ends2) { kidx = 2; off = ends1; }
    else if (gp < ends3) { kidx = 3; off = ends2; }
    else                 { kidx = 4; off = ends3; }
    int Nk = (30 - kidx) * 512;
    int local = gp - off;

    int r = lane >> 4, c16 = lane & 15;

    const int* rbase = rind + (size_t)kidx * (MAXN_ * NEG_) + (size_t)local * NEG_ + r;
    int rv0 = rbase[0], rv1 = rbase[4], rv2 = rbase[8], rv3 = rbase[12];
    int i0 = rv0 >= Nk ? rv0 - Nk : rv0;
    int i1 = rv1 >= Nk ? rv1 - Nk : rv1;
    int i2 = rv2 >= Nk ? rv2 - Nk : rv2;
    int i3 = rv3 >= Nk ? rv3 - Nk : rv3;

    const u8* zb = ztwk8 + (size_t)off * 256 + c16 * 16;
    uint4 nb0 = *reinterpret_cast<const uint4*>(zb + (size_t)i0 * 256);
    uint4 nb1 = *reinterpret_cast<const uint4*>(zb + (size_t)i1 * 256);
    uint4 nb2 = *reinterpret_cast<const uint4*>(zb + (size_t)i2 * 256);
    uint4 nb3 = *reinterpret_cast<const uint4*>(zb + (size_t)i3 * 256);

    uint4 cw4 = *reinterpret_cast<const uint4*>(ct8 + (size_t)local * 256 + c16 * 16);
    f32x2 cp[8];
    cp[0] = __builtin_amdgcn_cvt_pk_f32_fp8(cw4.x, false);
    cp[1] = __builtin_amdgcn_cvt_pk_f32_fp8(cw4.x, true);
    cp[2] = __builtin_amdgcn_cvt_pk_f32_fp8(cw4.y, false);
    cp[3] = __builtin_amdgcn_cvt_pk_f32_fp8(cw4.y, true);
    cp[4] = __builtin_amdgcn_cvt_pk_f32_fp8(cw4.z, false);
    cp[5] = __builtin_amdgcn_cvt_pk_f32_fp8(cw4.z, true);
    cp[6] = __builtin_amdgcn_cvt_pk_f32_fp8(cw4.w, false);
    cp[7] = __builtin_amdgcn_cvt_pk_f32_fp8(cw4.w, true);

    float d0 = dot16(nb0, cp);
    float d1 = dot16(nb1, cp);
    float d2 = dot16(nb2, cp);
    float d3 = dot16(nb3, cp);

    d0 += __shfl_xor(d0, 1); d1 += __shfl_xor(d1, 1);
    d2 += __shfl_xor(d2, 1); d3 += __shfl_xor(d3, 1);
    d0 += __shfl_xor(d0, 2); d1 += __shfl_xor(d1, 2);
    d2 += __shfl_xor(d2, 2); d3 += __shfl_xor(d3, 2);
    d0 += __shfl_xor(d0, 4); d1 += __shfl_xor(d1, 4);
    d2 += __shfl_xor(d2, 4); d3 += __shfl_xor(d3, 4);
    d0 += __shfl_xor(d0, 8); d1 += __shfl_xor(d1, 8);
    d2 += __shfl_xor(d2, 8); d3 += __shfl_xor(d3, 8);

    float h = fmaxf(0.f, 1.f + d0) + fmaxf(0.f, 1.f + d1)
            + fmaxf(0.f, 1.f + d2) + fmaxf(0.f, 1.f + d3);

    float val = h * (1.0f / 16.0f);
    val += __shfl_xor(val, 16);
    val += __shfl_xor(val, 32);
    val *= 1.0f / (float)Nk;

    if (lane == 0) partials[gp] = val;
}

// ---------------- single-block reduction ----------------
__global__ __launch_bounds__(1024) void reduce_kernel(
    const float* __restrict__ comb, float* __restrict__ out)
{
    __shared__ float s[16];
    float a = 0.f;
    for (int i = threadIdx.x; i < NPARTS; i += 1024) a += comb[i];
#pragma unroll
    for (int t = 1; t < 64; t <<= 1) a += __shfl_xor(a, t);
    int w = threadIdx.x >> 6, lane = threadIdx.x & 63;
    if (lane == 0) s[w] = a;
    __syncthreads();
    if (threadIdx.x < 16) {
        float v = s[threadIdx.x];
#pragma unroll
        for (int t = 1; t < 16; t <<= 1) v += __shfl_xor(v, t);
        if (threadIdx.x == 0) out[0] = v;
    }
}

extern "C" void kernel_launch(void* const* d_in, const int* in_sizes, int n_in,
                              void* d_out, int out_size, void* d_ws, size_t ws_size,
                              hipStream_t stream) {
    const float* z    = (const float*)d_in[0];
    const float* c    = (const float*)d_in[1];
    const float* W    = (const float*)d_in[2];
    const int*   rind = (const int*)d_in[3];

    char* ws = (char*)d_ws;
    u16*   ztr     = (u16*)  (ws + 0);            // 16384*256*2 = 8,388,608 (frag-major)
    u8*    ct8     = (u8*)   (ws + 8388608);      // 15360*256   = 3,932,160 (fp8)
    u8*    ztwk8   = (u8*)   (ws + 12320768);     // 71680*256   = 18,350,080
    float* parts   = (float*)(ws + 30670848);     // 71680*4     = 286,720
    float* posPart = (float*)(ws + 30957568);     // 1120*4      = 4,480 (contiguous)
    u16*   Wbf     = (u16*)  (ws + 30962048);     // 327680*2    = 655,360 (frag-major)
    float* out     = (float*)d_out;

    transpose_kernel<<<dim3(512, 4, 3), 256, 0, stream>>>(z, c, W, ztr, ct8, Wbf);
    gemm_mfma_kernel<<<dim3(NPOSP), 256, 0, stream>>>(ztr, Wbf, ct8, ztwk8, posPart);
    score_kernel<<<dim3(8960), 512, 0, stream>>>(ztwk8, ct8, rind, parts);
    reduce_kernel<<<dim3(1), 1024, 0, stream>>>(parts, out);
}

// Round 11
// 71.511 us; speedup vs baseline: 1.2676x; 1.2676x over previous
//
#include <hip/hip_runtime.h>

// ContrastiveLoss: B=16, C=256, H=32, Wd=32, K=5, SKIP=1, NEG=16
// r8-proven structure + flattened gemm grid + single merged reduction.
//   1) transpose: z -> ztr (bf16 frag-major, r5/r8 path); c -> ct8 (fp8); W -> Wbf
//   2) MFMA GEMM (flat 1120-block grid, r8 inner loop), fp8 out + fused positive hinge
//   3) score: 4 waves/block, wave per position (r8 verbatim), XCD-chunked swizzle
//   4) merged reduction over [score 17920 | gemm 1120] partials -> d_out[0]

typedef unsigned short u16;
typedef unsigned char u8;
typedef unsigned int u32;
typedef __attribute__((ext_vector_type(8))) short bf16x8;
typedef __attribute__((ext_vector_type(4))) float f32x4;
typedef __attribute__((ext_vector_type(2))) float f32x2;

#define NEG_  16
#define MAXN_ 15360   // (32-1-1)*32*16
#define TOTROWS 71680 // sum_k (30-kidx)*512
#define NSCORE 17920  // TOTROWS/4
#define NPOSP  1120   // flattened gemm blocks: 8*(30+29+28+27+26)
#define NPARTS (NSCORE + NPOSP)

__device__ __forceinline__ u16 f2bf(float f) {
    union { u32 i; float f; } v; v.f = f;
    u32 b = v.i;
    return (u16)((b + 0x7FFFu + ((b >> 16) & 1u)) >> 16);
}

__device__ __forceinline__ size_t frag_addr(int row, int k) {
    return ((size_t)(row >> 4) * 8 + (k >> 5)) * 512
         + (size_t)((row & 15) + 16 * ((k >> 3) & 3)) * 8 + (k & 7);
}

// ---------------- transpose + wconv (r8 verbatim) ----------------
__global__ __launch_bounds__(256) void transpose_kernel(
    const float* __restrict__ z, const float* __restrict__ cc,
    const float* __restrict__ W,
    u16* __restrict__ ztr, u8* __restrict__ ct8, u16* __restrict__ Wbf)
{
    int tid = threadIdx.x;
    if (blockIdx.z == 2) {
        if (blockIdx.y != 0 || blockIdx.x >= 320) return;
        int i4 = blockIdx.x * 256 + tid;
        float4 v = reinterpret_cast<const float4*>(W)[i4];
        int e = i4 * 4;
        int kw = e >> 16;
        int rem = e & 65535;
        int o = rem >> 8, c = rem & 255;
        size_t base = (size_t)kw * 65536 + frag_addr(o, c);
        ushort4 u;
        u.x = f2bf(v.x); u.y = f2bf(v.y); u.z = f2bf(v.z); u.w = f2bf(v.w);
        *reinterpret_cast<ushort4*>(Wbf + base) = u;
        return;
    }
    int by = blockIdx.x;
    int b = by >> 5, y = by & 31;
    int c0 = blockIdx.y * 64;
    bool is_c = (blockIdx.z == 1);
    if (is_c && y >= 30) return;
    const float* src = is_c ? cc : z;

    __shared__ float ts[64][33];
    int x = tid & 31, ci0 = tid >> 5;
#pragma unroll
    for (int i = 0; i < 8; ++i) {
        int ci = ci0 + i * 8;
        ts[ci][x] = src[(((size_t)b * 256 + c0 + ci) * 32 + y) * 32 + x];
    }
    __syncthreads();
    int cw = tid & 63, xw0 = tid >> 6;
    if (is_c) {
#pragma unroll
        for (int i = 0; i < 8; ++i) {
            int xw = xw0 + i * 4;
            float v = ts[cw][xw];
            u32 pk = __builtin_amdgcn_cvt_pk_fp8_f32(v, v, 0, false);
            ct8[(((size_t)y * 32 + xw) * 16 + b) * 256 + c0 + cw] = (u8)pk;
        }
    } else {
        int k = c0 + cw;
#pragma unroll
        for (int i = 0; i < 8; ++i) {
            int xw = xw0 + i * 4;
            int row = (y * 32 + xw) * 16 + b;
            ztr[frag_addr(row, k)] = f2bf(ts[cw][xw]);
        }
    }
}

// ---------------- MFMA GEMM, fp8 out + fused positive ----------------
// Flattened 1120-block grid; inner loop/epilogue are r8 verbatim.
__global__ __launch_bounds__(256) void gemm_mfma_kernel(
    const u16* __restrict__ ztr, const u16* __restrict__ Wbf,
    const u8* __restrict__ ct8,
    u8* __restrict__ ztwk8, float* __restrict__ posPart)
{
    int flat = blockIdx.x;
    int kidx, base;
    if (flat < 240)      { kidx = 0; base = 0; }
    else if (flat < 472) { kidx = 1; base = 240; }
    else if (flat < 696) { kidx = 2; base = 472; }
    else if (flat < 912) { kidx = 3; base = 696; }
    else                 { kidx = 4; base = 912; }
    int row0 = (flat - base) * 64;
    int offk = 512 * (30 * kidx - (kidx * (kidx - 1)) / 2);

    int tile0 = (((kidx + 2) * 512 + row0) >> 4);
    const u16* Bsw = Wbf + (size_t)kidx * 65536;
    u8* out = ztwk8 + ((size_t)offk + row0) * 256;

    int wid = threadIdx.x >> 6, lane = threadIdx.x & 63;
    int col0 = wid * 64;

    f32x4 acc[4][4] = {};

    for (int kb = 0; kb < 8; ++kb) {
        bf16x8 a[4], b[4];
#pragma unroll
        for (int i = 0; i < 4; ++i)
            a[i] = *reinterpret_cast<const bf16x8*>(
                ztr + ((size_t)(tile0 + i) * 8 + kb) * 512 + lane * 8);
#pragma unroll
        for (int j = 0; j < 4; ++j)
            b[j] = *reinterpret_cast<const bf16x8*>(
                Bsw + ((size_t)(wid * 4 + j) * 8 + kb) * 512 + lane * 8);
#pragma unroll
        for (int i = 0; i < 4; ++i)
#pragma unroll
            for (int j = 0; j < 4; ++j)
                acc[i][j] = __builtin_amdgcn_mfma_f32_16x16x32_bf16(b[j], a[i], acc[i][j], 0, 0, 0);
    }

    int lr = lane & 15;
    int rq = (lane >> 4) * 4;
    __shared__ float pos[4][64];

#pragma unroll
    for (int i = 0; i < 4; ++i) {
        int local = row0 + i * 16 + lr;
        float pp = 0.f;
#pragma unroll
        for (int j = 0; j < 4; ++j) {
            u32 u = 0;
            u = __builtin_amdgcn_cvt_pk_fp8_f32(acc[i][j][0], acc[i][j][1], u, false);
            u = __builtin_amdgcn_cvt_pk_fp8_f32(acc[i][j][2], acc[i][j][3], u, true);
            *reinterpret_cast<u32*>(out + (size_t)(i * 16 + lr) * 256 + col0 + j * 16 + rq) = u;
            u32 cw_ = *reinterpret_cast<const u32*>(ct8 + (size_t)local * 256 + col0 + j * 16 + rq);
            f32x2 clo = __builtin_amdgcn_cvt_pk_f32_fp8(cw_, false);
            f32x2 chi = __builtin_amdgcn_cvt_pk_f32_fp8(cw_, true);
            pp = fmaf(acc[i][j][0], clo.x, pp);
            pp = fmaf(acc[i][j][1], clo.y, pp);
            pp = fmaf(acc[i][j][2], chi.x, pp);
            pp = fmaf(acc[i][j][3], chi.y, pp);
        }
        pp += __shfl_xor(pp, 16);
        pp += __shfl_xor(pp, 32);
        if (lane < 16) pos[wid][i * 16 + lane] = pp;
    }
    __syncthreads();

    if (threadIdx.x < 64) {
        float p = pos[0][threadIdx.x] + pos[1][threadIdx.x]
                + pos[2][threadIdx.x] + pos[3][threadIdx.x];
        float Nk = (float)((30 - kidx) * 512);
        float h = fmaxf(0.f, 1.f - p) / Nk;
#pragma unroll
        for (int s = 1; s < 64; s <<= 1) h += __shfl_xor(h, s);
        if (threadIdx.x == 0) posPart[flat] = h;
    }
}

// ---------------- negative scores + hinge (r8 verbatim) ----------------
__device__ __forceinline__ float dot16(uint4 nb, const f32x2* cp) {
    f32x2 d0 = {0.f, 0.f}, d1 = {0.f, 0.f};
    d0 += __builtin_amdgcn_cvt_pk_f32_fp8(nb.x, false) * cp[0];
    d1 += __builtin_amdgcn_cvt_pk_f32_fp8(nb.x, true)  * cp[1];
    d0 += __builtin_amdgcn_cvt_pk_f32_fp8(nb.y, false) * cp[2];
    d1 += __builtin_amdgcn_cvt_pk_f32_fp8(nb.y, true)  * cp[3];
    d0 += __builtin_amdgcn_cvt_pk_f32_fp8(nb.z, false) * cp[4];
    d1 += __builtin_amdgcn_cvt_pk_f32_fp8(nb.z, true)  * cp[5];
    d0 += __builtin_amdgcn_cvt_pk_f32_fp8(nb.w, false) * cp[6];
    d1 += __builtin_amdgcn_cvt_pk_f32_fp8(nb.w, true)  * cp[7];
    f32x2 d = d0 + d1;
    return d.x + d.y;
}

__global__ __launch_bounds__(256) void score_kernel(
    const u8* __restrict__ ztwk8, const u8* __restrict__ ct8,
    const int* __restrict__ rind, float* __restrict__ partials)
{
    __shared__ float red[4];
    int bid = blockIdx.x;
    int swb = (bid & 7) * 2240 + (bid >> 3);
    int wid = threadIdx.x >> 6, lane = threadIdx.x & 63;
    int gp = swb * 4 + wid;

    const int ends0 = 15360, ends1 = 30208, ends2 = 44544, ends3 = 58368;
    int kidx, off;
    if (gp < ends0)      { kidx = 0; off = 0; }
    else if (gp < ends1) { kidx = 1; off = ends0; }
    else if (gp < ends2) { kidx = 2; off = ends1; }
    else if (gp < ends3) { kidx = 3; off = ends2; }
    else                 { kidx = 4; off = ends3; }
    int Nk = (30 - kidx) * 512;
    int local = gp - off;

    int r = lane >> 4, c16 = lane & 15;

    const int* rbase = rind + (size_t)kidx * (MAXN_ * NEG_) + (size_t)local * NEG_ + r;
    int rv0 = rbase[0], rv1 = rbase[4], rv2 = rbase[8], rv3 = rbase[12];
    int i0 = rv0 >= Nk ? rv0 - Nk : rv0;
    int i1 = rv1 >= Nk ? rv1 - Nk : rv1;
    int i2 = rv2 >= Nk ? rv2 - Nk : rv2;
    int i3 = rv3 >= Nk ? rv3 - Nk : rv3;

    const u8* zb = ztwk8 + (size_t)off * 256 + c16 * 16;
    uint4 nb0 = *reinterpret_cast<const uint4*>(zb + (size_t)i0 * 256);
    uint4 nb1 = *reinterpret_cast<const uint4*>(zb + (size_t)i1 * 256);
    uint4 nb2 = *reinterpret_cast<const uint4*>(zb + (size_t)i2 * 256);
    uint4 nb3 = *reinterpret_cast<const uint4*>(zb + (size_t)i3 * 256);

    uint4 cw4 = *reinterpret_cast<const uint4*>(ct8 + (size_t)local * 256 + c16 * 16);
    f32x2 cp[8];
    cp[0] = __builtin_amdgcn_cvt_pk_f32_fp8(cw4.x, false);
    cp[1] = __builtin_amdgcn_cvt_pk_f32_fp8(cw4.x, true);
    cp[2] = __builtin_amdgcn_cvt_pk_f32_fp8(cw4.y, false);
    cp[3] = __builtin_amdgcn_cvt_pk_f32_fp8(cw4.y, true);
    cp[4] = __builtin_amdgcn_cvt_pk_f32_fp8(cw4.z, false);
    cp[5] = __builtin_amdgcn_cvt_pk_f32_fp8(cw4.z, true);
    cp[6] = __builtin_amdgcn_cvt_pk_f32_fp8(cw4.w, false);
    cp[7] = __builtin_amdgcn_cvt_pk_f32_fp8(cw4.w, true);

    float d, h = 0.f;
    d = dot16(nb0, cp);
    d += __shfl_xor(d, 1); d += __shfl_xor(d, 2);
    d += __shfl_xor(d, 4); d += __shfl_xor(d, 8);
    h += fmaxf(0.f, 1.f + d);
    d = dot16(nb1, cp);
    d += __shfl_xor(d, 1); d += __shfl_xor(d, 2);
    d += __shfl_xor(d, 4); d += __shfl_xor(d, 8);
    h += fmaxf(0.f, 1.f + d);
    d = dot16(nb2, cp);
    d += __shfl_xor(d, 1); d += __shfl_xor(d, 2);
    d += __shfl_xor(d, 4); d += __shfl_xor(d, 8);
    h += fmaxf(0.f, 1.f + d);
    d = dot16(nb3, cp);
    d += __shfl_xor(d, 1); d += __shfl_xor(d, 2);
    d += __shfl_xor(d, 4); d += __shfl_xor(d, 8);
    h += fmaxf(0.f, 1.f + d);

    float val = h * (1.0f / 16.0f);
    val += __shfl_xor(val, 16);
    val += __shfl_xor(val, 32);
    val *= 1.0f / (float)Nk;

    if (lane == 0) red[wid] = val;
    __syncthreads();
    if (threadIdx.x == 0)
        partials[bid] = red[0] + red[1] + red[2] + red[3];
}

// ---------------- merged single-block reduction ----------------
__global__ __launch_bounds__(1024) void reduce_kernel(
    const float* __restrict__ comb, float* __restrict__ out)
{
    __shared__ float s[16];
    float a = 0.f;
    for (int i = threadIdx.x; i < NPARTS; i += 1024) a += comb[i];
#pragma unroll
    for (int t = 1; t < 64; t <<= 1) a += __shfl_xor(a, t);
    int w = threadIdx.x >> 6, lane = threadIdx.x & 63;
    if (lane == 0) s[w] = a;
    __syncthreads();
    if (threadIdx.x < 16) {
        float v = s[threadIdx.x];
#pragma unroll
        for (int t = 1; t < 16; t <<= 1) v += __shfl_xor(v, t);
        if (threadIdx.x == 0) out[0] = v;
    }
}

extern "C" void kernel_launch(void* const* d_in, const int* in_sizes, int n_in,
                              void* d_out, int out_size, void* d_ws, size_t ws_size,
                              hipStream_t stream) {
    const float* z    = (const float*)d_in[0];
    const float* c    = (const float*)d_in[1];
    const float* W    = (const float*)d_in[2];
    const int*   rind = (const int*)d_in[3];

    char* ws = (char*)d_ws;
    u16*   ztr     = (u16*)  (ws + 0);            // 16384*256*2 = 8,388,608 (frag-major)
    u8*    ct8     = (u8*)   (ws + 8388608);      // 15360*256   = 3,932,160 (fp8)
    u8*    ztwk8   = (u8*)   (ws + 12320768);     // 71680*256   = 18,350,080
    float* parts   = (float*)(ws + 30670848);     // NSCORE*4    = 71,680
    float* posPart = (float*)(ws + 30742528);     // NPOSP*4     = 4,480 (contiguous after parts)
    u16*   Wbf     = (u16*)  (ws + 30747008);     // 327680*2    = 655,360 (frag-major)
    float* out     = (float*)d_out;

    transpose_kernel<<<dim3(512, 4, 3), 256, 0, stream>>>(z, c, W, ztr, ct8, Wbf);
    gemm_mfma_kernel<<<dim3(NPOSP), 256, 0, stream>>>(ztr, Wbf, ct8, ztwk8, posPart);
    score_kernel<<<dim3(NSCORE), 256, 0, stream>>>(ztwk8, ct8, rind, parts);
    reduce_kernel<<<dim3(1), 1024, 0, stream>>>(parts, out);
}